// Round 1
// baseline (622.942 us; speedup 1.0000x reference)
//
#include <hip/hip_runtime.h>
#include <math.h>

// ---------------------------------------------------------------------------
// Restormer-style TransformerBlock on MI355X (gfx950)
// B=4, C=192, H=W=128, N=HW=16384, heads=8, ch/head=24, hidden=510
// All big tensors [B][C][N] (NCHW). bf16 (ushort) intermediates, fp32 residual.
// ---------------------------------------------------------------------------

typedef __attribute__((ext_vector_type(8))) short short8;
typedef __attribute__((ext_vector_type(4))) float f32x4;

#define DEVI __device__ __forceinline__

DEVI unsigned short f2bf(float f) {
  union { float f; unsigned u; } v; v.f = f;
  unsigned r = v.u + 0x7fffu + ((v.u >> 16) & 1u);   // RNE
  return (unsigned short)(r >> 16);
}
DEVI float bf2f(unsigned short h) {
  union { unsigned u; float f; } v; v.u = ((unsigned)h) << 16;
  return v.f;
}

// ---------------------------------------------------------------------------
// K0: convert + zero-pad weights to bf16
//   wq [576][192], wi [1024][192] (rows >=1020 zero), wo [192][512] (cols>=510 zero)
// ---------------------------------------------------------------------------
__global__ __launch_bounds__(256) void k_convert_w(
    const float* __restrict__ qkv_w, const float* __restrict__ ffn_in_w,
    const float* __restrict__ ffn_out_w,
    unsigned short* __restrict__ wq, unsigned short* __restrict__ wi,
    unsigned short* __restrict__ wo) {
  int idx = blockIdx.x * 256 + threadIdx.x;
  if (idx < 576 * 192) wq[idx] = f2bf(qkv_w[idx]);
  if (idx < 1024 * 192) {
    int o = idx / 192;
    wi[idx] = (o < 1020) ? f2bf(ffn_in_w[idx]) : (unsigned short)0;
  }
  if (idx < 192 * 512) {
    int o = idx >> 9, c = idx & 511;
    wo[idx] = (c < 510) ? f2bf(ffn_out_w[o * 510 + c]) : (unsigned short)0;
  }
}

__global__ __launch_bounds__(256) void k_zero(float* __restrict__ p, int n) {
  int i = blockIdx.x * 256 + threadIdx.x;
  if (i < n) p[i] = 0.f;
}

// ---------------------------------------------------------------------------
// LayerNorm over channel dim: in fp32 [B][192][N] -> out bf16 [B][192][N]
// one thread per spatial position, two passes over 192 channels
// ---------------------------------------------------------------------------
__global__ __launch_bounds__(256) void k_ln(
    const float* __restrict__ x, const float* __restrict__ g,
    const float* __restrict__ bta, unsigned short* __restrict__ y) {
  int idx = blockIdx.x * 256 + threadIdx.x;   // B*N = 65536
  int b = idx >> 14, n = idx & 16383;
  const float* px = x + (((size_t)b * 192) << 14) + n;
  float s = 0.f, ss = 0.f;
#pragma unroll 4
  for (int c = 0; c < 192; c++) {
    float v = px[(size_t)c << 14];
    s += v; ss += v * v;
  }
  float mu = s * (1.f / 192.f);
  float var = ss * (1.f / 192.f) - mu * mu;
  float rs = rsqrtf(var + 1e-5f);
  unsigned short* py = y + (((size_t)b * 192) << 14) + n;
#pragma unroll 4
  for (int c = 0; c < 192; c++) {
    float v = px[(size_t)c << 14];
    py[(size_t)c << 14] = f2bf((v - mu) * rs * g[c] + bta[c]);
  }
}

// ---------------------------------------------------------------------------
// GEMM: out[b][o][n] = sum_c W[o][c] * in[b][c][n]   (+ optional fp32 residual)
//  in  : bf16 [B][C][N] (pointer may be pre-offset to a channel base)
//  W   : bf16 [OPAD][CPAD], zero-padded; optionally per-batch (w_bstride)
//  EPI : 0 -> bf16 store to out; 1 -> fp32 store out = resid + acc
// Block: 256 thr (4 waves), tile 128 spatial x 64 out-ch chunks, MFMA 16x16x32
// LDS tile transposed to [n][c], row stride KCHUNK+8 shorts (odd # of 16B units)
// ---------------------------------------------------------------------------
template <int C, int CPAD, int O, int OPAD, int KCHUNK, int EPI>
__global__ __launch_bounds__(256) void k_gemm(
    const unsigned short* __restrict__ in, size_t in_bstride,
    const unsigned short* __restrict__ W, int w_bstride,
    const float* __restrict__ resid, void* __restrict__ outp) {
  constexpr int N = 16384;
  constexpr int RS = KCHUNK + 8;
  __shared__ unsigned short lds[128 * RS];
  int t = threadIdx.x;
  int b = blockIdx.y;
  int n0 = blockIdx.x * 128;
  const unsigned short* inb = in + (size_t)b * in_bstride;
  const unsigned short* Wb = W + (size_t)b * (size_t)w_bstride;
  int wv = t >> 6, lane = t & 63, lrow = lane & 15, lhi = lane >> 4;
  int sn = t & 127, sc0 = (t >> 7) * 8;
  constexpr int NKC = CPAD / KCHUNK;

  for (int oc = 0; oc < OPAD / 64; ++oc) {
    f32x4 acc[4][2];
#pragma unroll
    for (int i = 0; i < 4; i++)
#pragma unroll
      for (int j = 0; j < 2; j++) acc[i][j] = (f32x4){0.f, 0.f, 0.f, 0.f};

    for (int kci = 0; kci < NKC; ++kci) {
      int kc0 = kci * KCHUNK;
      if (NKC > 1 || oc == 0) {
        __syncthreads();   // protect LDS from readers of previous chunk
#pragma unroll
        for (int cg = sc0; cg < KCHUNK; cg += 16) {
          short8 v;
#pragma unroll
          for (int j = 0; j < 8; j++) {
            int cglob = kc0 + cg + j;
            unsigned short u = (C == CPAD || cglob < C)
                ? inb[((size_t)cglob << 14) + n0 + sn] : (unsigned short)0;
            v[j] = (short)u;
          }
          *reinterpret_cast<short8*>(&lds[sn * RS + cg]) = v;
        }
      }
      __syncthreads();
#pragma unroll
      for (int ks = 0; ks < KCHUNK; ks += 32) {
        short8 b0 = *reinterpret_cast<const short8*>(
            &lds[(wv * 32 + lrow) * RS + ks + lhi * 8]);
        short8 b1 = *reinterpret_cast<const short8*>(
            &lds[(wv * 32 + 16 + lrow) * RS + ks + lhi * 8]);
#pragma unroll
        for (int oi = 0; oi < 4; ++oi) {
          short8 a = *reinterpret_cast<const short8*>(
              &Wb[(size_t)(oc * 64 + oi * 16 + lrow) * CPAD + kc0 + ks + lhi * 8]);
          acc[oi][0] = __builtin_amdgcn_mfma_f32_16x16x32_bf16(a, b0, acc[oi][0], 0, 0, 0);
          acc[oi][1] = __builtin_amdgcn_mfma_f32_16x16x32_bf16(a, b1, acc[oi][1], 0, 0, 0);
        }
      }
    }
    // epilogue: D lane map col = lane&15, row = 4*(lane>>4)+r
#pragma unroll
    for (int oi = 0; oi < 4; ++oi) {
      int obase = oc * 64 + oi * 16 + lhi * 4;
#pragma unroll
      for (int nf = 0; nf < 2; ++nf) {
        int n = n0 + wv * 32 + nf * 16 + lrow;
#pragma unroll
        for (int r = 0; r < 4; r++) {
          int oo = obase + r;
          if (OPAD == O || oo < O) {
            size_t idx = (((size_t)(b * O + oo)) << 14) + n;
            if (EPI == 0)
              ((unsigned short*)outp)[idx] = f2bf(acc[oi][nf][r]);
            else
              ((float*)outp)[idx] = resid[idx] + acc[oi][nf][r];
          }
        }
      }
    }
  }
}

// ---------------------------------------------------------------------------
// Depthwise 3x3 (pad 1), H=W=128. 8 outputs per thread along w.
//  FUSE=0: plain, CC channels in == out (qkv path, CC=576)
//  FUSE=1: channels c and c+510 of 1020-ch input -> gelu(d1)*d2, 510-ch output
// ---------------------------------------------------------------------------
template <int FUSE>
__global__ __launch_bounds__(256) void k_dwconv(
    const unsigned short* __restrict__ in, const float* __restrict__ wt,
    unsigned short* __restrict__ out) {
  constexpr int CC = FUSE ? 510 : 576;    // output channels
  constexpr int CIN = FUSE ? 1020 : 576;  // input channels
  int idx = blockIdx.x * 256 + threadIdx.x;
  int per_b = CC << 11;                   // CC * 2048 (H*W/8)
  int b = idx / per_b;
  int rem = idx - b * per_b;
  int c = rem >> 11;
  int hw8 = rem & 2047;
  int h = hw8 >> 4;
  int w0 = (hw8 & 15) << 3;

  float ov[FUSE ? 2 : 1][8];
#pragma unroll
  for (int s = 0; s < (FUSE ? 2 : 1); s++) {
    int ch = c + s * 510;
    float k9[9];
#pragma unroll
    for (int q = 0; q < 9; q++) k9[q] = wt[ch * 9 + q];
    float v[3][10];
    const unsigned short* base = in + (((size_t)b * CIN + ch) << 14);
#pragma unroll
    for (int dh = 0; dh < 3; dh++) {
      int hh = h + dh - 1;
      if (hh < 0 || hh > 127) {
#pragma unroll
        for (int j = 0; j < 10; j++) v[dh][j] = 0.f;
      } else {
        const unsigned short* rp = base + (hh << 7) + w0;
        short8 m = *reinterpret_cast<const short8*>(rp);
#pragma unroll
        for (int j = 0; j < 8; j++) v[dh][j + 1] = bf2f((unsigned short)m[j]);
        v[dh][0] = (w0 > 0) ? bf2f(rp[-1]) : 0.f;
        v[dh][9] = (w0 < 120) ? bf2f(rp[8]) : 0.f;
      }
    }
#pragma unroll
    for (int j = 0; j < 8; j++) {
      float a = 0.f;
#pragma unroll
      for (int dh = 0; dh < 3; dh++)
#pragma unroll
        for (int dw = 0; dw < 3; dw++) a += k9[dh * 3 + dw] * v[dh][j + dw];
      ov[s][j] = a;
    }
  }
  short8 res;
  if (FUSE == 0) {
#pragma unroll
    for (int j = 0; j < 8; j++) res[j] = (short)f2bf(ov[0][j]);
  } else {
#pragma unroll
    for (int j = 0; j < 8; j++) {
      float x1 = ov[0][j], x2 = ov[1][j];
      float gl = 0.5f * x1 * (1.f + erff(x1 * 0.70710678118654752f));
      res[j] = (short)f2bf(gl * x2);
    }
  }
  unsigned short* ob = out + (((size_t)b * CC + c) << 14) + (h << 7) + w0;
  *reinterpret_cast<short8*>(ob) = res;
}

// ---------------------------------------------------------------------------
// Gram: G[b][h][48][48] += stacked . stacked^T over n, stacked = [q_h ; k_h]
// rows 0..23 = q channels h*24.., rows 24..47 = k channels 192+h*24..
// grid (8 slices, 8 heads, 4 batch), block 256 (4 waves), fp32 atomics out.
// Only upper-triangle block tiles (j>=i) are computed/emitted.
// ---------------------------------------------------------------------------
__global__ __launch_bounds__(256) void k_gram(
    const unsigned short* __restrict__ qkvd, float* __restrict__ G) {
  constexpr int RS = 520;   // 512+8 shorts, 65 (odd) 16B units per row
  __shared__ unsigned short lds[48 * RS];
  int t = threadIdx.x;
  int slice = blockIdx.x, h = blockIdx.y, b = blockIdx.z;
  int wv = t >> 6, lane = t & 63, lrow = lane & 15, lhi = lane >> 4;
  f32x4 D00 = {0.f,0.f,0.f,0.f}, D01 = D00, D02 = D00, D11 = D00, D12 = D00, D22 = D00;
  int nbase = slice * 2048;
  for (int round = 0; round < 4; ++round) {
    int n0 = nbase + round * 512;
    __syncthreads();
    for (int i = t; i < 48 * 64; i += 256) {
      int row = i >> 6, col8 = i & 63;
      int ch = (row < 24) ? (h * 24 + row) : (192 + h * 24 + row - 24);
      short8 v = *reinterpret_cast<const short8*>(
          &qkvd[(((size_t)b * 576 + ch) << 14) + n0 + col8 * 8]);
      *reinterpret_cast<short8*>(&lds[row * RS + col8 * 8]) = v;
    }
    __syncthreads();
#pragma unroll
    for (int ks = 0; ks < 4; ++ks) {
      int coff = wv * 128 + ks * 32 + lhi * 8;
      short8 f0 = *reinterpret_cast<const short8*>(&lds[(0 + lrow) * RS + coff]);
      short8 f1 = *reinterpret_cast<const short8*>(&lds[(16 + lrow) * RS + coff]);
      short8 f2 = *reinterpret_cast<const short8*>(&lds[(32 + lrow) * RS + coff]);
      D00 = __builtin_amdgcn_mfma_f32_16x16x32_bf16(f0, f0, D00, 0, 0, 0);
      D01 = __builtin_amdgcn_mfma_f32_16x16x32_bf16(f0, f1, D01, 0, 0, 0);
      D02 = __builtin_amdgcn_mfma_f32_16x16x32_bf16(f0, f2, D02, 0, 0, 0);
      D11 = __builtin_amdgcn_mfma_f32_16x16x32_bf16(f1, f1, D11, 0, 0, 0);
      D12 = __builtin_amdgcn_mfma_f32_16x16x32_bf16(f1, f2, D12, 0, 0, 0);
      D22 = __builtin_amdgcn_mfma_f32_16x16x32_bf16(f2, f2, D22, 0, 0, 0);
    }
  }
  float* Gh = G + (size_t)(b * 8 + h) * 48 * 48;
#define EMIT(Dv, i, j)                                                        \
  {                                                                           \
    _Pragma("unroll") for (int r = 0; r < 4; r++)                             \
        atomicAdd(&Gh[(16 * (i) + lhi * 4 + r) * 48 + 16 * (j) + lrow], Dv[r]); \
  }
  EMIT(D00, 0, 0); EMIT(D01, 0, 1); EMIT(D02, 0, 2);
  EMIT(D11, 1, 1); EMIT(D12, 1, 2); EMIT(D22, 2, 2);
#undef EMIT
}

// ---------------------------------------------------------------------------
// softmax over attention logits; A[b][h][c][d]
// logits = G_qk[c][d] / (max(|q_c|,eps)*max(|k_d|,eps)) * temp[h]
// ---------------------------------------------------------------------------
__global__ __launch_bounds__(256) void k_attnsm(
    const float* __restrict__ G, const float* __restrict__ temp,
    float* __restrict__ A) {
  int idx = blockIdx.x * 256 + threadIdx.x;   // 4*8*24 = 768
  if (idx >= 4 * 8 * 24) return;
  int b = idx / (8 * 24);
  int rem = idx - b * 8 * 24;
  int h = rem / 24, c = rem % 24;
  const float* Gh = G + (size_t)(b * 8 + h) * 48 * 48;
  float tpr = temp[h];
  float nq = fmaxf(sqrtf(fmaxf(Gh[c * 48 + c], 0.f)), 1e-12f);
  float lg[24];
  float mx = -1e30f;
#pragma unroll
  for (int d = 0; d < 24; d++) {
    float nk = fmaxf(sqrtf(fmaxf(Gh[(24 + d) * 48 + 24 + d], 0.f)), 1e-12f);
    float l = Gh[c * 48 + 24 + d] / (nq * nk) * tpr;
    lg[d] = l;
    mx = fmaxf(mx, l);
  }
  float s = 0.f;
#pragma unroll
  for (int d = 0; d < 24; d++) { lg[d] = expf(lg[d] - mx); s += lg[d]; }
  float inv = 1.f / s;
  float* Ar = A + (size_t)idx * 24;
#pragma unroll
  for (int d = 0; d < 24; d++) Ar[d] = lg[d] * inv;
}

// ---------------------------------------------------------------------------
// Fold proj_w with per-head attention into per-batch M[b][o][h*24+d] (bf16)
// M[o][(h,d)] = sum_ch P[o][h*24+ch] * A[b][h][ch][d]
// ---------------------------------------------------------------------------
__global__ __launch_bounds__(256) void k_foldM(
    const float* __restrict__ A, const float* __restrict__ P,
    unsigned short* __restrict__ M) {
  int idx = blockIdx.x * 256 + threadIdx.x;   // 4*192*192
  if (idx >= 4 * 192 * 192) return;
  int b = idx / (192 * 192);
  int rem = idx - b * 192 * 192;
  int o = rem / 192, cd = rem % 192;
  int h = cd / 24, d = cd % 24;
  const float* Ah = A + (size_t)(b * 8 + h) * 24 * 24;
  const float* Pr = P + o * 192 + h * 24;
  float s = 0.f;
#pragma unroll
  for (int ch = 0; ch < 24; ch++) s += Pr[ch] * Ah[ch * 24 + d];
  M[idx] = f2bf(s);
}

// ---------------------------------------------------------------------------
extern "C" void kernel_launch(void* const* d_in, const int* in_sizes, int n_in,
                              void* d_out, int out_size, void* d_ws,
                              size_t ws_size, hipStream_t stream) {
  const float* x          = (const float*)d_in[0];
  const float* ln2_w      = (const float*)d_in[1];
  const float* ln2_b      = (const float*)d_in[2];
  const float* qkv_w      = (const float*)d_in[3];
  const float* qkv_dw_w   = (const float*)d_in[4];
  const float* temperature= (const float*)d_in[5];
  const float* attn_proj_w= (const float*)d_in[6];
  const float* ln3_w      = (const float*)d_in[7];
  const float* ln3_b      = (const float*)d_in[8];
  const float* ffn_in_w   = (const float*)d_in[9];
  const float* ffn_dw_w   = (const float*)d_in[10];
  const float* ffn_out_w  = (const float*)d_in[11];

  unsigned char* ws = (unsigned char*)d_ws;
  size_t off = 0;
  auto alloc = [&](size_t bytes) -> void* {
    void* p = ws + off;
    off = (off + bytes + 255) & ~(size_t)255;
    return p;
  };
  // lifetime-overlapped slots:
  //  S1: y (LN2 out) -> qkvd (dwconv out) -> hbuf (ffn_in out, 1020 ch)
  //  S2: qkv (gemm out) -> y3 (LN3 out) -> g (gated ffn hidden, 510 ch)
  unsigned short* S1  = (unsigned short*)alloc(133693440); // 1020*16384*2*4
  unsigned short* S2  = (unsigned short*)alloc(75497472);  // 576*16384*2*4
  float*          out1= (float*)alloc(50331648);           // 192*16384*4*4
  unsigned short* wq  = (unsigned short*)alloc(221184);    // 576*192*2
  unsigned short* wi  = (unsigned short*)alloc(393216);    // 1024*192*2
  unsigned short* wo  = (unsigned short*)alloc(196608);    // 192*512*2
  unsigned short* Mw  = (unsigned short*)alloc(294912);    // 4*192*192*2
  float*          G   = (float*)alloc(294912);             // 4*8*48*48*4
  float*          Aat = (float*)alloc(73728);              // 4*8*24*24*4

  // K0: weight conversion (+ zero G)
  k_convert_w<<<768, 256, 0, stream>>>(qkv_w, ffn_in_w, ffn_out_w, wq, wi, wo);
  k_zero<<<288, 256, 0, stream>>>(G, 4 * 8 * 48 * 48);

  // K1: LN2(x) -> y (bf16) in S1
  k_ln<<<256, 256, 0, stream>>>(x, ln2_w, ln2_b, S1);

  // K2: qkv = y @ Wqkv^T  -> S2 (bf16 [B][576][N])
  k_gemm<192, 192, 576, 576, 192, 0><<<dim3(128, 4), 256, 0, stream>>>(
      S1, (size_t)192 << 14, wq, 0, nullptr, S2);

  // K3: dwconv 3x3 on qkv -> qkvd in S1 (overwrites y; y dead)
  k_dwconv<0><<<18432, 256, 0, stream>>>(S2, qkv_dw_w, S1);

  // K4: Gram of [q;k] per (b,head) -> G (fp32 atomics)
  k_gram<<<dim3(8, 8, 4), 256, 0, stream>>>(S1, G);

  // K5: softmax -> Aat ; fold with proj -> per-batch M (bf16)
  k_attnsm<<<3, 256, 0, stream>>>(G, temperature, Aat);
  k_foldM<<<576, 256, 0, stream>>>(Aat, attn_proj_w, Mw);

  // K6: z = M[b] @ v ; out1 = x + z (fp32). v = qkvd channels 384..575
  k_gemm<192, 192, 192, 192, 192, 1><<<dim3(128, 4), 256, 0, stream>>>(
      S1 + ((size_t)384 << 14), (size_t)576 << 14, Mw, 192 * 192, x, out1);

  // K7: LN3(out1) -> y3 (bf16) in S2 (qkv dead)
  k_ln<<<256, 256, 0, stream>>>(out1, ln3_w, ln3_b, S2);

  // K8: hbuf = y3 @ Win^T -> S1 (bf16 [B][1020][N]) (qkvd dead)
  k_gemm<192, 192, 1020, 1024, 192, 0><<<dim3(128, 4), 256, 0, stream>>>(
      S2, (size_t)192 << 14, wi, 0, nullptr, S1);

  // K9: dwconv pairs + gelu gate -> g in S2 (bf16 [B][510][N]) (y3 dead)
  k_dwconv<1><<<16320, 256, 0, stream>>>(S1, ffn_dw_w, S2);

  // K10: f = g @ Wout^T ; d_out = out1 + f (fp32)
  k_gemm<510, 512, 192, 192, 128, 1><<<dim3(128, 4), 256, 0, stream>>>(
      S2, (size_t)510 << 14, wo, 0, out1, (float*)d_out);
}

// Round 2
// 465.901 us; speedup vs baseline: 1.3371x; 1.3371x over previous
//
#include <hip/hip_runtime.h>
#include <math.h>

// ---------------------------------------------------------------------------
// Restormer-style TransformerBlock on MI355X (gfx950)
// B=4, C=192, H=W=128, N=HW=16384, heads=8, ch/head=24, hidden=510
// bf16 intermediates in [B][N][C] (channel-contiguous) layout; fp32 residual
// stream stays [B][C][N] (matches input x and required output layout).
// GEMMs: weight chunk in LDS (XOR-swizzled), activations as B-fragments
// straight from global (16B/lane, coalesced). No transpose staging.
// ---------------------------------------------------------------------------

typedef __attribute__((ext_vector_type(8))) short short8;
typedef __attribute__((ext_vector_type(4))) short short4v;
typedef __attribute__((ext_vector_type(4))) float f32x4;

#define DEVI __device__ __forceinline__

DEVI unsigned short f2bf(float f) {
  union { float f; unsigned u; } v; v.f = f;
  unsigned r = v.u + 0x7fffu + ((v.u >> 16) & 1u);   // RNE
  return (unsigned short)(r >> 16);
}
DEVI float bf2f(unsigned short h) {
  union { unsigned u; float f; } v; v.u = ((unsigned)h) << 16;
  return v.f;
}

// ---------------------------------------------------------------------------
// K0: convert + zero-pad weights to bf16.
//  wq [576][192]  = qkv_w
//  wi [1024][192] : row o<510 -> ffn_in row o ; rows 510,511 -> 0 ;
//                   rows 512..1021 -> ffn_in rows 510..1019 ; 1022,1023 -> 0
//                   (so gelu pairs land at h-cols c and 512+c, both aligned)
//  wo [192][512]  : cols >=510 zero
// ---------------------------------------------------------------------------
__global__ __launch_bounds__(256) void k_convert_w(
    const float* __restrict__ qkv_w, const float* __restrict__ ffn_in_w,
    const float* __restrict__ ffn_out_w,
    unsigned short* __restrict__ wq, unsigned short* __restrict__ wi,
    unsigned short* __restrict__ wo) {
  int idx = blockIdx.x * 256 + threadIdx.x;
  if (idx < 576 * 192) wq[idx] = f2bf(qkv_w[idx]);
  if (idx < 1024 * 192) {
    int o = idx / 192, c = idx - o * 192;
    int src = (o < 510) ? o : ((o >= 512 && o < 1022) ? o - 2 : -1);
    wi[idx] = (src >= 0) ? f2bf(ffn_in_w[src * 192 + c]) : (unsigned short)0;
  }
  if (idx < 192 * 512) {
    int o = idx >> 9, c = idx & 511;
    wo[idx] = (c < 510) ? f2bf(ffn_out_w[o * 510 + c]) : (unsigned short)0;
  }
}

__global__ __launch_bounds__(256) void k_zero(float* __restrict__ p, int n) {
  int i = blockIdx.x * 256 + threadIdx.x;
  if (i < n) p[i] = 0.f;
}

// ---------------------------------------------------------------------------
// LayerNorm over channels: in fp32 [B][192][N] -> out bf16 [B][N][192]
// thread = (n, c-half of 96); single pass, stats combined via shfl_xor(1).
// ---------------------------------------------------------------------------
__global__ __launch_bounds__(256) void k_ln(
    const float* __restrict__ x, const float* __restrict__ g,
    const float* __restrict__ bta, unsigned short* __restrict__ y) {
  int idx = blockIdx.x * 256 + threadIdx.x;   // 2 * B*N = 131072
  int half = idx & 1;
  int n = idx >> 1;                            // 0..65535
  int b = n >> 14, nn = n & 16383;
  int c0 = half * 96;
  const float* px = x + (((size_t)b * 192 + c0) << 14) + nn;
  float v[96];
  float s = 0.f, ss = 0.f;
#pragma unroll
  for (int j = 0; j < 96; j++) {
    v[j] = px[(size_t)j << 14];
    s += v[j]; ss += v[j] * v[j];
  }
  s += __shfl_xor(s, 1, 64);
  ss += __shfl_xor(ss, 1, 64);
  float mu = s * (1.f / 192.f);
  float var = ss * (1.f / 192.f) - mu * mu;
  float rs = rsqrtf(var + 1e-5f);
  unsigned short* py = y + ((((size_t)b << 14) + nn) * 192) + c0;
#pragma unroll
  for (int j8 = 0; j8 < 12; j8++) {
    short8 o8;
#pragma unroll
    for (int k = 0; k < 8; k++) {
      int c = c0 + j8 * 8 + k;
      o8[k] = (short)f2bf((v[j8 * 8 + k] - mu) * rs * g[c] + bta[c]);
    }
    *reinterpret_cast<short8*>(py + j8 * 8) = o8;
  }
}

// ---------------------------------------------------------------------------
// GEMM: out[o][n] = sum_c W[o][c] * in[n][c]
//  in  : bf16 [B][N][RSIN] rows (pointer may be column-offset)
//  W   : bf16 [O][C] global (optional per-batch stride wbs)
//  LDS : weight chunk [OCHUNK][C], 16B-slot XOR swizzle (slot ^= o&7)
//  B-fragments straight from global. 8 waves; each wave NB*16 rows of n.
//  EPI 0: bf16 store to out[N][rsout] at col (ocb+o)
//  EPI 1: fp32 store out[(b*192+o)<<14 | n] = resid[idx] + acc
// ---------------------------------------------------------------------------
template <int C, int OCHUNK, int NB, int EPI>
__global__ __launch_bounds__(512) void k_gemm(
    const unsigned short* __restrict__ in, int rsin,
    const unsigned short* __restrict__ W, int wbs,
    const float* __restrict__ resid, void* __restrict__ outp, int rsout) {
  constexpr int SLOTS = C / 8;
  __shared__ unsigned short lds[OCHUNK * C];
  int t = threadIdx.x;
  int b = blockIdx.z;
  int ocb = blockIdx.y * OCHUNK;
  int wv = t >> 6, lane = t & 63, lrow = lane & 15, lhi = lane >> 4;

  // stage weight chunk -> LDS (swizzled)
  const unsigned short* Wb = W + (size_t)b * wbs;
#pragma unroll
  for (int i = t; i < OCHUNK * SLOTS; i += 512) {
    int o = i / SLOTS, s = i - o * SLOTS;
    short8 v = *reinterpret_cast<const short8*>(&Wb[(size_t)(ocb + o) * C + s * 8]);
    *reinterpret_cast<short8*>(&lds[(o * SLOTS + (s ^ (o & 7))) * 8]) = v;
  }

  // B fragments from global (held across the whole o-loop)
  size_t nbase = ((size_t)b << 14) + blockIdx.x * (128 * NB) + wv * (16 * NB);
  short8 bf[NB][C / 32];
#pragma unroll
  for (int nb = 0; nb < NB; nb++) {
    const unsigned short* prow = in + (nbase + nb * 16 + lrow) * rsin + lhi * 8;
#pragma unroll
    for (int k = 0; k < C / 32; k++)
      bf[nb][k] = *reinterpret_cast<const short8*>(prow + k * 32);
  }
  __syncthreads();

  for (int ot = 0; ot < OCHUNK / 16; ++ot) {
    f32x4 acc[NB];
#pragma unroll
    for (int nb = 0; nb < NB; nb++) acc[nb] = (f32x4){0.f, 0.f, 0.f, 0.f};
    int orow = ot * 16 + lrow;
#pragma unroll
    for (int k = 0; k < C / 32; k++) {
      short8 a = *reinterpret_cast<const short8*>(
          &lds[(orow * SLOTS + ((k * 4 + lhi) ^ (lrow & 7))) * 8]);
#pragma unroll
      for (int nb = 0; nb < NB; nb++)
        acc[nb] = __builtin_amdgcn_mfma_f32_16x16x32_bf16(a, bf[nb][k], acc[nb], 0, 0, 0);
    }
#pragma unroll
    for (int nb = 0; nb < NB; nb++) {
      size_t n = nbase + nb * 16 + lrow;   // includes b*16384
      if (EPI == 0) {
        short4v pk;
#pragma unroll
        for (int r = 0; r < 4; r++) pk[r] = (short)f2bf(acc[nb][r]);
        *reinterpret_cast<short4v*>(
            (unsigned short*)outp + n * rsout + ocb + ot * 16 + lhi * 4) = pk;
      } else {
        int nn = (int)(n & 16383);
#pragma unroll
        for (int r = 0; r < 4; r++) {
          int og = ocb + ot * 16 + lhi * 4 + r;
          size_t idx = (((size_t)(b * 192 + og)) << 14) + nn;
          ((float*)outp)[idx] = resid[idx] + acc[nb][r];
        }
      }
    }
  }
}

// ---------------------------------------------------------------------------
// Depthwise 3x3 (pad 1) on [B][N][Crow] layout. Thread = 4 n (along w) x 4 ch.
//  FUSE=0: qkv path, 576 ch in/out
//  FUSE=1: gelu(dw(x1)) * dw(x2); x1 at cols c, x2 at cols 512+c of [N][1024];
//          out [N][512] (cols 510,511 produce 0 since weights forced 0)
// ---------------------------------------------------------------------------
template <int FUSE>
__global__ __launch_bounds__(256) void k_dwconv(
    const unsigned short* __restrict__ in, const float* __restrict__ wt,
    unsigned short* __restrict__ out) {
  constexpr int NC4 = FUSE ? 128 : 144;
  constexpr int RSI = FUSE ? 1024 : 576;
  constexpr int RSO = FUSE ? 512 : 576;
  int idx = blockIdx.x * 256 + threadIdx.x;
  int cq = idx % NC4;
  int ngg = idx / NC4;
  int b = ngg >> 12, ng = ngg & 4095;
  int n0 = ng * 4, h = n0 >> 7, w0 = n0 & 127;
  size_t rowb = ((size_t)b << 14);
  int c4 = cq * 4;

  float acc1[4][4], acc2[4][4];
#pragma unroll
  for (int j = 0; j < 4; j++)
#pragma unroll
    for (int i = 0; i < 4; i++) { acc1[j][i] = 0.f; acc2[j][i] = 0.f; }

#pragma unroll
  for (int s = 0; s <= (FUSE ? 1 : 0); s++) {
    float wv[4][9];
#pragma unroll
    for (int i = 0; i < 4; i++) {
      int ch = c4 + i;
      bool valid = FUSE ? (ch < 510) : true;
      int wrow = FUSE ? (s ? 510 + ch : ch) : ch;
#pragma unroll
      for (int q = 0; q < 9; q++) wv[i][q] = valid ? wt[wrow * 9 + q] : 0.f;
    }
    int colb = (FUSE && s) ? 512 + c4 : c4;
#pragma unroll
    for (int dh = 0; dh < 3; dh++) {
      int hh = h + dh - 1;
      bool hv = (hh >= 0) && (hh < 128);
      float f[6][4];
#pragma unroll
      for (int p = 0; p < 6; p++) {
        int ww = w0 + p - 1;
        bool v2 = hv && (ww >= 0) && (ww < 128);
        short4v raw = {0, 0, 0, 0};
        if (v2)
          raw = *reinterpret_cast<const short4v*>(
              &in[(rowb + (hh << 7) + ww) * RSI + colb]);
#pragma unroll
        for (int i = 0; i < 4; i++) f[p][i] = bf2f((unsigned short)raw[i]);
      }
#pragma unroll
      for (int j = 0; j < 4; j++)
#pragma unroll
        for (int i = 0; i < 4; i++) {
          float a = (s == 0) ? acc1[j][i] : acc2[j][i];
#pragma unroll
          for (int dw = 0; dw < 3; dw++) a += wv[i][dh * 3 + dw] * f[j + dw][i];
          if (s == 0) acc1[j][i] = a; else acc2[j][i] = a;
        }
    }
  }
#pragma unroll
  for (int j = 0; j < 4; j++) {
    short4v o4;
#pragma unroll
    for (int i = 0; i < 4; i++) {
      float val;
      if (FUSE) {
        float x1 = acc1[j][i];
        float gl = 0.5f * x1 * (1.f + erff(x1 * 0.70710678118654752f));
        val = gl * acc2[j][i];
      } else {
        val = acc1[j][i];
      }
      o4[i] = (short)f2bf(val);
    }
    *reinterpret_cast<short4v*>(&out[(rowb + n0 + j) * RSO + c4]) = o4;
  }
}

// ---------------------------------------------------------------------------
// Gram: G[b][h][48][48] += stacked.stacked^T, stacked rows = [q_h ; k_h],
// reduction over n. qkvd is [B][N][576]; q_h cols h*24.., k_h cols 192+h*24..
// LDS tile transposed to [48 c][256 n] (pad RS=264); A/B frags are identical
// b128 reads. grid (16 n-splits, 8 heads, 4 b); 4 waves split the k(n) chunks;
// fp32 atomics accumulate partials. Upper-triangle block tiles only.
// ---------------------------------------------------------------------------
__global__ __launch_bounds__(256) void k_gram(
    const unsigned short* __restrict__ qkvd, float* __restrict__ G) {
  constexpr int RS = 264;
  __shared__ unsigned short lds[48 * RS];
  int t = threadIdx.x;
  int nsp = blockIdx.x, h = blockIdx.y, b = blockIdx.z;
  int lane = t & 63, wv = t >> 6, lrow = lane & 15, lhi = lane >> 4;
  f32x4 D00 = {0.f,0.f,0.f,0.f}, D01 = D00, D02 = D00, D11 = D00, D12 = D00, D22 = D00;
  size_t rb = (size_t)b << 14;
  int qb = h * 24, kb = 192 + h * 24;

  for (int rnd = 0; rnd < 4; ++rnd) {
    int n0 = nsp * 1024 + rnd * 256;
    __syncthreads();
#pragma unroll
    for (int part = 0; part < 2; part++) {
      int cb = part ? kb : qb;
#pragma unroll
      for (int ch8 = 0; ch8 < 3; ch8++) {
        short8 v = *reinterpret_cast<const short8*>(
            &qkvd[(rb + n0 + t) * 576 + cb + ch8 * 8]);
#pragma unroll
        for (int j = 0; j < 8; j++)
          lds[(part * 24 + ch8 * 8 + j) * RS + t] = (unsigned short)v[j];
      }
    }
    __syncthreads();
#pragma unroll
    for (int st = 0; st < 2; st++) {
      int noff = (wv * 2 + st) * 32 + lhi * 8;
      short8 f0 = *reinterpret_cast<const short8*>(&lds[(0 + lrow) * RS + noff]);
      short8 f1 = *reinterpret_cast<const short8*>(&lds[(16 + lrow) * RS + noff]);
      short8 f2 = *reinterpret_cast<const short8*>(&lds[(32 + lrow) * RS + noff]);
      D00 = __builtin_amdgcn_mfma_f32_16x16x32_bf16(f0, f0, D00, 0, 0, 0);
      D01 = __builtin_amdgcn_mfma_f32_16x16x32_bf16(f0, f1, D01, 0, 0, 0);
      D02 = __builtin_amdgcn_mfma_f32_16x16x32_bf16(f0, f2, D02, 0, 0, 0);
      D11 = __builtin_amdgcn_mfma_f32_16x16x32_bf16(f1, f1, D11, 0, 0, 0);
      D12 = __builtin_amdgcn_mfma_f32_16x16x32_bf16(f1, f2, D12, 0, 0, 0);
      D22 = __builtin_amdgcn_mfma_f32_16x16x32_bf16(f2, f2, D22, 0, 0, 0);
    }
  }
  float* Gh = G + (size_t)(b * 8 + h) * 48 * 48;
#define EMIT(Dv, i, j)                                                          \
  {                                                                             \
    _Pragma("unroll") for (int r = 0; r < 4; r++)                               \
        atomicAdd(&Gh[(16 * (i) + lhi * 4 + r) * 48 + 16 * (j) + lrow], Dv[r]); \
  }
  EMIT(D00, 0, 0); EMIT(D01, 0, 1); EMIT(D02, 0, 2);
  EMIT(D11, 1, 1); EMIT(D12, 1, 2); EMIT(D22, 2, 2);
#undef EMIT
}

// ---------------------------------------------------------------------------
// softmax of logits built from Gram; A[b][h][c][d]
// ---------------------------------------------------------------------------
__global__ __launch_bounds__(256) void k_attnsm(
    const float* __restrict__ G, const float* __restrict__ temp,
    float* __restrict__ A) {
  int idx = blockIdx.x * 256 + threadIdx.x;   // 768
  if (idx >= 4 * 8 * 24) return;
  int b = idx / (8 * 24);
  int rem = idx - b * 8 * 24;
  int h = rem / 24, c = rem % 24;
  const float* Gh = G + (size_t)(b * 8 + h) * 48 * 48;
  float tpr = temp[h];
  float nq = fmaxf(sqrtf(fmaxf(Gh[c * 48 + c], 0.f)), 1e-12f);
  float lg[24];
  float mx = -1e30f;
#pragma unroll
  for (int d = 0; d < 24; d++) {
    float nk = fmaxf(sqrtf(fmaxf(Gh[(24 + d) * 48 + 24 + d], 0.f)), 1e-12f);
    float l = Gh[c * 48 + 24 + d] / (nq * nk) * tpr;
    lg[d] = l;
    mx = fmaxf(mx, l);
  }
  float s = 0.f;
#pragma unroll
  for (int d = 0; d < 24; d++) { lg[d] = expf(lg[d] - mx); s += lg[d]; }
  float inv = 1.f / s;
  float* Ar = A + (size_t)idx * 24;
#pragma unroll
  for (int d = 0; d < 24; d++) Ar[d] = lg[d] * inv;
}

// ---------------------------------------------------------------------------
// Fold proj_w with per-head attention: M[b][o][h*24+d] (bf16, [192][192]/batch)
// ---------------------------------------------------------------------------
__global__ __launch_bounds__(256) void k_foldM(
    const float* __restrict__ A, const float* __restrict__ P,
    unsigned short* __restrict__ M) {
  int idx = blockIdx.x * 256 + threadIdx.x;   // 4*192*192
  if (idx >= 4 * 192 * 192) return;
  int b = idx / (192 * 192);
  int rem = idx - b * 192 * 192;
  int o = rem / 192, cd = rem % 192;
  int h = cd / 24, d = cd % 24;
  const float* Ah = A + (size_t)(b * 8 + h) * 24 * 24;
  const float* Pr = P + o * 192 + h * 24;
  float s = 0.f;
#pragma unroll
  for (int ch = 0; ch < 24; ch++) s += Pr[ch] * Ah[ch * 24 + d];
  M[idx] = f2bf(s);
}

// ---------------------------------------------------------------------------
extern "C" void kernel_launch(void* const* d_in, const int* in_sizes, int n_in,
                              void* d_out, int out_size, void* d_ws,
                              size_t ws_size, hipStream_t stream) {
  const float* x          = (const float*)d_in[0];
  const float* ln2_w      = (const float*)d_in[1];
  const float* ln2_b      = (const float*)d_in[2];
  const float* qkv_w      = (const float*)d_in[3];
  const float* qkv_dw_w   = (const float*)d_in[4];
  const float* temperature= (const float*)d_in[5];
  const float* attn_proj_w= (const float*)d_in[6];
  const float* ln3_w      = (const float*)d_in[7];
  const float* ln3_b      = (const float*)d_in[8];
  const float* ffn_in_w   = (const float*)d_in[9];
  const float* ffn_dw_w   = (const float*)d_in[10];
  const float* ffn_out_w  = (const float*)d_in[11];

  unsigned char* ws = (unsigned char*)d_ws;
  size_t off = 0;
  auto alloc = [&](size_t bytes) -> void* {
    void* p = ws + off;
    off = (off + bytes + 255) & ~(size_t)255;
    return p;
  };
  // S1: qkv [B][N][576] -> h [B][N][1024]
  // S2: y [B][N][192] -> qkvd [B][N][576] -> y3 [B][N][192] -> g [B][N][512]
  unsigned short* S1  = (unsigned short*)alloc(134217728); // 4*16384*1024*2
  unsigned short* S2  = (unsigned short*)alloc(75497472);  // 4*16384*576*2
  float*          out1= (float*)alloc(50331648);           // 4*192*16384*4
  unsigned short* wq  = (unsigned short*)alloc(221184);
  unsigned short* wi  = (unsigned short*)alloc(393216);
  unsigned short* wo  = (unsigned short*)alloc(196608);
  unsigned short* Mw  = (unsigned short*)alloc(294912);
  float*          G   = (float*)alloc(294912);
  float*          Aat = (float*)alloc(73728);

  // K0: weight conversion (+ zero G)
  k_convert_w<<<768, 256, 0, stream>>>(qkv_w, ffn_in_w, ffn_out_w, wq, wi, wo);
  k_zero<<<288, 256, 0, stream>>>(G, 4 * 8 * 48 * 48);

  // K1: LN2(x) -> y bf16 [B][N][192] (S2)
  k_ln<<<512, 256, 0, stream>>>(x, ln2_w, ln2_b, S2);

  // K2: qkv[n][o] = y @ wq^T -> S1 [B][N][576]
  k_gemm<192, 192, 2, 0><<<dim3(64, 3, 4), 512, 0, stream>>>(
      S2, 192, wq, 0, nullptr, S1, 576);

  // K3: dwconv on qkv -> qkvd (S2)
  k_dwconv<0><<<9216, 256, 0, stream>>>(S1, qkv_dw_w, S2);

  // K4: Gram of [q;k] -> G (fp32 atomics)
  k_gram<<<dim3(16, 8, 4), 256, 0, stream>>>(S2, G);

  // K5: softmax -> Aat ; fold with proj -> M
  k_attnsm<<<3, 256, 0, stream>>>(G, temperature, Aat);
  k_foldM<<<576, 256, 0, stream>>>(Aat, attn_proj_w, Mw);

  // K6: out1 = x + M[b] @ v   (v = qkvd cols 384..575)
  k_gemm<192, 192, 2, 1><<<dim3(64, 1, 4), 512, 0, stream>>>(
      S2 + 384, 576, Mw, 192 * 192, x, out1, 0);

  // K7: LN3(out1) -> y3 bf16 [B][N][192] (S2, qkvd dead)
  k_ln<<<512, 256, 0, stream>>>(out1, ln3_w, ln3_b, S2);

  // K8: h = y3 @ wi^T -> S1 [B][N][1024] (qkv dead)
  k_gemm<192, 128, 2, 0><<<dim3(64, 8, 4), 512, 0, stream>>>(
      S2, 192, wi, 0, nullptr, S1, 1024);

  // K9: dwconv pairs + gelu gate -> g [B][N][512] (S2, y3 dead)
  k_dwconv<1><<<8192, 256, 0, stream>>>(S1, ffn_dw_w, S2);

  // K10: d_out = out1 + g @ wo^T  (fp32 [B][192][N])
  k_gemm<512, 64, 1, 1><<<dim3(128, 3, 4), 512, 0, stream>>>(
      S2, 512, wo, 0, out1, d_out, 0);
}

// Round 3
// 410.284 us; speedup vs baseline: 1.5183x; 1.1356x over previous
//
#include <hip/hip_runtime.h>
#include <math.h>

// ---------------------------------------------------------------------------
// Restormer-style TransformerBlock on MI355X (gfx950)
// B=4, C=192, H=W=128, N=HW=16384, heads=8, ch/head=24, hidden=510
// bf16 intermediates in [B][N][C]; residual path: x fp32 [C][N] (input),
// out1 bf16 [N][192], final d_out fp32 [C][N].
// ---------------------------------------------------------------------------

typedef __attribute__((ext_vector_type(8))) short short8;
typedef __attribute__((ext_vector_type(4))) short short4v;
typedef __attribute__((ext_vector_type(4))) float f32x4;

#define DEVI __device__ __forceinline__

DEVI unsigned short f2bf(float f) {
  union { float f; unsigned u; } v; v.f = f;
  unsigned r = v.u + 0x7fffu + ((v.u >> 16) & 1u);   // RNE
  return (unsigned short)(r >> 16);
}
DEVI float bf2f(unsigned short h) {
  union { unsigned u; float f; } v; v.u = ((unsigned)h) << 16;
  return v.f;
}

// ---------------------------------------------------------------------------
// K0: convert + zero-pad weights to bf16.
// ---------------------------------------------------------------------------
__global__ __launch_bounds__(256) void k_convert_w(
    const float* __restrict__ qkv_w, const float* __restrict__ ffn_in_w,
    const float* __restrict__ ffn_out_w,
    unsigned short* __restrict__ wq, unsigned short* __restrict__ wi,
    unsigned short* __restrict__ wo) {
  int idx = blockIdx.x * 256 + threadIdx.x;
  if (idx < 576 * 192) wq[idx] = f2bf(qkv_w[idx]);
  if (idx < 1024 * 192) {
    int o = idx / 192, c = idx - o * 192;
    int src = (o < 510) ? o : ((o >= 512 && o < 1022) ? o - 2 : -1);
    wi[idx] = (src >= 0) ? f2bf(ffn_in_w[src * 192 + c]) : (unsigned short)0;
  }
  if (idx < 192 * 512) {
    int o = idx >> 9, c = idx & 511;
    wo[idx] = (c < 510) ? f2bf(ffn_out_w[o * 510 + c]) : (unsigned short)0;
  }
}

__global__ __launch_bounds__(256) void k_zero(float* __restrict__ p, int n) {
  int i = blockIdx.x * 256 + threadIdx.x;
  if (i < n) p[i] = 0.f;
}

// ---------------------------------------------------------------------------
// LN2: fp32 [B][192][N] -> bf16 [B][N][192]
// ---------------------------------------------------------------------------
__global__ __launch_bounds__(256) void k_ln(
    const float* __restrict__ x, const float* __restrict__ g,
    const float* __restrict__ bta, unsigned short* __restrict__ y) {
  int idx = blockIdx.x * 256 + threadIdx.x;   // 2 * B*N = 131072
  int half = idx & 1;
  int n = idx >> 1;
  int b = n >> 14, nn = n & 16383;
  int c0 = half * 96;
  const float* px = x + (((size_t)b * 192 + c0) << 14) + nn;
  float v[96];
  float s = 0.f, ss = 0.f;
#pragma unroll
  for (int j = 0; j < 96; j++) {
    v[j] = px[(size_t)j << 14];
    s += v[j]; ss += v[j] * v[j];
  }
  s += __shfl_xor(s, 1, 64);
  ss += __shfl_xor(ss, 1, 64);
  float mu = s * (1.f / 192.f);
  float var = ss * (1.f / 192.f) - mu * mu;
  float rs = rsqrtf(var + 1e-5f);
  unsigned short* py = y + ((((size_t)b << 14) + nn) * 192) + c0;
#pragma unroll
  for (int j8 = 0; j8 < 12; j8++) {
    short8 o8;
#pragma unroll
    for (int k = 0; k < 8; k++) {
      int c = c0 + j8 * 8 + k;
      o8[k] = (short)f2bf((v[j8 * 8 + k] - mu) * rs * g[c] + bta[c]);
    }
    *reinterpret_cast<short8*>(py + j8 * 8) = o8;
  }
}

// ---------------------------------------------------------------------------
// LN3: bf16 [B*N][192] -> bf16 [B*N][192]   (contiguous rows)
// ---------------------------------------------------------------------------
__global__ __launch_bounds__(256) void k_ln_bf(
    const unsigned short* __restrict__ in, const float* __restrict__ g,
    const float* __restrict__ bta, unsigned short* __restrict__ out) {
  int n = blockIdx.x * 256 + threadIdx.x;    // 65536
  const unsigned short* p = in + (size_t)n * 192;
  short8 raw[24];
  float s = 0.f, ss = 0.f;
#pragma unroll
  for (int j = 0; j < 24; j++) {
    raw[j] = *reinterpret_cast<const short8*>(p + j * 8);
#pragma unroll
    for (int k = 0; k < 8; k++) {
      float f = bf2f((unsigned short)raw[j][k]);
      s += f; ss += f * f;
    }
  }
  float mu = s * (1.f / 192.f);
  float var = ss * (1.f / 192.f) - mu * mu;
  float rs = rsqrtf(var + 1e-5f);
  unsigned short* q = out + (size_t)n * 192;
#pragma unroll
  for (int j = 0; j < 24; j++) {
    short8 o8;
#pragma unroll
    for (int k = 0; k < 8; k++) {
      int c = j * 8 + k;
      float f = bf2f((unsigned short)raw[j][k]);
      o8[k] = (short)f2bf((f - mu) * rs * g[c] + bta[c]);
    }
    *reinterpret_cast<short8*>(q + j * 8) = o8;
  }
}

// ---------------------------------------------------------------------------
// GEMM: out[o][n] = sum_c W[o][c] * in[n][c]
//  EPI 0: bf16 store to out[N][rsout] at col
//  EPI 2: bf16 store to out[N][192]: f2bf(residF[(b*192+o)<<14|nn] + acc)
//  EPI 3: fp32 store d_out[(b*192+o)<<14|nn] = bf2f(residB[n*192+o]) + acc
// ---------------------------------------------------------------------------
template <int C, int OCHUNK, int NB, int EPI>
__global__ __launch_bounds__(512) void k_gemm(
    const unsigned short* __restrict__ in, int rsin,
    const unsigned short* __restrict__ W, int wbs,
    const float* __restrict__ residF, const unsigned short* __restrict__ residB,
    void* __restrict__ outp, int rsout) {
  constexpr int SLOTS = C / 8;
  __shared__ unsigned short lds[OCHUNK * C];
  int t = threadIdx.x;
  int b = blockIdx.z;
  int ocb = blockIdx.y * OCHUNK;
  int wv = t >> 6, lane = t & 63, lrow = lane & 15, lhi = lane >> 4;

  const unsigned short* Wb = W + (size_t)b * wbs;
#pragma unroll
  for (int i = t; i < OCHUNK * SLOTS; i += 512) {
    int o = i / SLOTS, s = i - o * SLOTS;
    short8 v = *reinterpret_cast<const short8*>(&Wb[(size_t)(ocb + o) * C + s * 8]);
    *reinterpret_cast<short8*>(&lds[(o * SLOTS + (s ^ (o & 7))) * 8]) = v;
  }

  size_t nbase = ((size_t)b << 14) + blockIdx.x * (128 * NB) + wv * (16 * NB);
  short8 bf[NB][C / 32];
#pragma unroll
  for (int nb = 0; nb < NB; nb++) {
    const unsigned short* prow = in + (nbase + nb * 16 + lrow) * rsin + lhi * 8;
#pragma unroll
    for (int k = 0; k < C / 32; k++)
      bf[nb][k] = *reinterpret_cast<const short8*>(prow + k * 32);
  }
  __syncthreads();

  for (int ot = 0; ot < OCHUNK / 16; ++ot) {
    f32x4 acc[NB];
#pragma unroll
    for (int nb = 0; nb < NB; nb++) acc[nb] = (f32x4){0.f, 0.f, 0.f, 0.f};
    int orow = ot * 16 + lrow;
#pragma unroll
    for (int k = 0; k < C / 32; k++) {
      short8 a = *reinterpret_cast<const short8*>(
          &lds[(orow * SLOTS + ((k * 4 + lhi) ^ (lrow & 7))) * 8]);
#pragma unroll
      for (int nb = 0; nb < NB; nb++)
        acc[nb] = __builtin_amdgcn_mfma_f32_16x16x32_bf16(a, bf[nb][k], acc[nb], 0, 0, 0);
    }
#pragma unroll
    for (int nb = 0; nb < NB; nb++) {
      size_t n = nbase + nb * 16 + lrow;   // includes b*16384
      int obase = ocb + ot * 16 + lhi * 4;
      if (EPI == 0) {
        short4v pk;
#pragma unroll
        for (int r = 0; r < 4; r++) pk[r] = (short)f2bf(acc[nb][r]);
        *reinterpret_cast<short4v*>((unsigned short*)outp + n * rsout + obase) = pk;
      } else if (EPI == 2) {
        int nn = (int)(n & 16383);
        short4v pk;
#pragma unroll
        for (int r = 0; r < 4; r++) {
          float rx = residF[(((size_t)(b * 192 + obase + r)) << 14) + nn];
          pk[r] = (short)f2bf(rx + acc[nb][r]);
        }
        *reinterpret_cast<short4v*>((unsigned short*)outp + n * 192 + obase) = pk;
      } else {   // EPI == 3
        int nn = (int)(n & 16383);
        short4v rb = *reinterpret_cast<const short4v*>(residB + n * 192 + obase);
#pragma unroll
        for (int r = 0; r < 4; r++) {
          size_t idx = (((size_t)(b * 192 + obase + r)) << 14) + nn;
          ((float*)outp)[idx] = bf2f((unsigned short)rb[r]) + acc[nb][r];
        }
      }
    }
  }
}

// ---------------------------------------------------------------------------
// Depthwise 3x3 (pad 1), LDS-tiled. Block 512 thr; tile = 16 ch x HT rows x
// 128 w (ROWS=HT+2 staged rows, w padded to [-1..128] -> width 130, edges 0).
//  FUSE=0: in [N][576] -> out [N][576]
//  FUSE=1: in [N][1024] cols c & 512+c -> gelu(d1)*d2 -> out [N][512]
// LDS planes of b64 (4ch) units: [row][set][g4][130]; compute reads are
// lanes-consecutive-w stride-8B => conflict-free; no bounds checks in loop.
// ---------------------------------------------------------------------------
template <int FUSE, int HT>
__global__ __launch_bounds__(512) void k_dwconv(
    const unsigned short* __restrict__ in, const float* __restrict__ wt,
    unsigned short* __restrict__ out) {
  constexpr int ROWS = HT + 2;
  constexpr int SETS = FUSE ? 2 : 1;
  constexpr int RSI = FUSE ? 1024 : 576;
  constexpr int RSO = FUSE ? 512 : 576;
  constexpr int WP = 130;
  __shared__ unsigned short lds[ROWS * SETS * 4 * WP * 4];

  int t = threadIdx.x;
  int h0 = blockIdx.x * HT;
  int ct0 = blockIdx.y * 16;
  int b = blockIdx.z;
  size_t bb = (size_t)b << 14;

  // zero the w-edge columns (wp=0 and wp=129) of every plane
  constexpr int PLANES = ROWS * SETS * 4;
  if (t < PLANES * 2) {
    int wp = (t & 1) * 129;
    int plane = t >> 1;
    *reinterpret_cast<short4v*>(&lds[(plane * WP + wp) * 4]) = (short4v){0, 0, 0, 0};
  }

  // stage ROWS x SETS x 128w x 16ch (b128 chunks of 8ch)
  constexpr int CHUNKS = ROWS * SETS * 2 * 128;
#pragma unroll
  for (int k = 0; k < CHUNKS / 512; ++k) {
    int id = t + k * 512;
    int c2 = id & 1;
    int w = (id >> 1) & 127;
    int rest = id >> 8;                       // wave-uniform
    int s = SETS == 2 ? (rest & 1) : 0;
    int row = SETS == 2 ? (rest >> 1) : rest;
    int grow = h0 - 1 + row;
    short8 v = {0, 0, 0, 0, 0, 0, 0, 0};
    if (grow >= 0 && grow < 128) {
      int col = (FUSE && s) ? (512 + ct0 + c2 * 8) : (ct0 + c2 * 8);
      v = *reinterpret_cast<const short8*>(
          &in[(bb + grow * 128 + w) * RSI + col]);
    }
    int plane = ((row * SETS + s) * 4 + c2 * 2) * WP;
    short4v lo = {v[0], v[1], v[2], v[3]}, hi = {v[4], v[5], v[6], v[7]};
    *reinterpret_cast<short4v*>(&lds[(plane + w + 1) * 4]) = lo;
    *reinterpret_cast<short4v*>(&lds[(plane + WP + w + 1) * 4]) = hi;
  }
  __syncthreads();

  int w = t & 127, g = t >> 7;                // g in 0..3, wave-uniform
  int ch0 = ct0 + g * 4;

  // weights -> (scalar) regs
  float wv[SETS][4][9];
#pragma unroll
  for (int s = 0; s < SETS; s++)
#pragma unroll
    for (int j = 0; j < 4; j++) {
      int ch = ch0 + j;
      bool vo = FUSE ? (ch < 510) : true;
      int wr = FUSE ? (s ? 510 + ch : ch) : ch;
#pragma unroll
      for (int q = 0; q < 9; q++) wv[s][j][q] = vo ? wt[wr * 9 + q] : 0.f;
    }

#pragma unroll
  for (int hs = 0; hs < HT; hs++) {
    float a1[4] = {0.f, 0.f, 0.f, 0.f}, a2[4] = {0.f, 0.f, 0.f, 0.f};
#pragma unroll
    for (int dr = 0; dr < 3; dr++) {
      int row = hs + dr;
#pragma unroll
      for (int s = 0; s < SETS; s++) {
        int pbase = ((row * SETS + s) * 4 + g) * WP;
#pragma unroll
        for (int pos = 0; pos < 3; pos++) {
          short4v r4 = *reinterpret_cast<const short4v*>(
              &lds[(pbase + w + pos) * 4]);
#pragma unroll
          for (int j = 0; j < 4; j++) {
            float f = bf2f((unsigned short)r4[j]);
            if (s == 0) a1[j] += wv[0][j][dr * 3 + pos] * f;
            else        a2[j] += wv[1][j][dr * 3 + pos] * f;
          }
        }
      }
    }
    size_t nout = bb + (h0 + hs) * 128 + w;
    short4v o4;
    if (FUSE) {
#pragma unroll
      for (int j = 0; j < 4; j++) {
        float x1 = a1[j];
        float gl = 0.5f * x1 * (1.f + erff(x1 * 0.70710678118654752f));
        o4[j] = (short)f2bf(gl * a2[j]);
      }
    } else {
#pragma unroll
      for (int j = 0; j < 4; j++) o4[j] = (short)f2bf(a1[j]);
    }
    *reinterpret_cast<short4v*>(&out[nout * RSO + ch0]) = o4;
  }
}

// ---------------------------------------------------------------------------
// Gram: G[b][h][48][48] += stacked.stacked^T (rows [q_h;k_h]), over n.
// ---------------------------------------------------------------------------
__global__ __launch_bounds__(256) void k_gram(
    const unsigned short* __restrict__ qkvd, float* __restrict__ G) {
  constexpr int RS = 264;
  __shared__ unsigned short lds[48 * RS];
  int t = threadIdx.x;
  int nsp = blockIdx.x, h = blockIdx.y, b = blockIdx.z;
  int lane = t & 63, wv = t >> 6, lrow = lane & 15, lhi = lane >> 4;
  f32x4 D00 = {0.f,0.f,0.f,0.f}, D01 = D00, D02 = D00, D11 = D00, D12 = D00, D22 = D00;
  size_t rb = (size_t)b << 14;
  int qb = h * 24, kb = 192 + h * 24;

  for (int rnd = 0; rnd < 4; ++rnd) {
    int n0 = nsp * 1024 + rnd * 256;
    __syncthreads();
#pragma unroll
    for (int part = 0; part < 2; part++) {
      int cb = part ? kb : qb;
#pragma unroll
      for (int ch8 = 0; ch8 < 3; ch8++) {
        short8 v = *reinterpret_cast<const short8*>(
            &qkvd[(rb + n0 + t) * 576 + cb + ch8 * 8]);
#pragma unroll
        for (int j = 0; j < 8; j++)
          lds[(part * 24 + ch8 * 8 + j) * RS + t] = (unsigned short)v[j];
      }
    }
    __syncthreads();
#pragma unroll
    for (int st = 0; st < 2; st++) {
      int noff = (wv * 2 + st) * 32 + lhi * 8;
      short8 f0 = *reinterpret_cast<const short8*>(&lds[(0 + lrow) * RS + noff]);
      short8 f1 = *reinterpret_cast<const short8*>(&lds[(16 + lrow) * RS + noff]);
      short8 f2 = *reinterpret_cast<const short8*>(&lds[(32 + lrow) * RS + noff]);
      D00 = __builtin_amdgcn_mfma_f32_16x16x32_bf16(f0, f0, D00, 0, 0, 0);
      D01 = __builtin_amdgcn_mfma_f32_16x16x32_bf16(f0, f1, D01, 0, 0, 0);
      D02 = __builtin_amdgcn_mfma_f32_16x16x32_bf16(f0, f2, D02, 0, 0, 0);
      D11 = __builtin_amdgcn_mfma_f32_16x16x32_bf16(f1, f1, D11, 0, 0, 0);
      D12 = __builtin_amdgcn_mfma_f32_16x16x32_bf16(f1, f2, D12, 0, 0, 0);
      D22 = __builtin_amdgcn_mfma_f32_16x16x32_bf16(f2, f2, D22, 0, 0, 0);
    }
  }
  float* Gh = G + (size_t)(b * 8 + h) * 48 * 48;
#define EMIT(Dv, i, j)                                                          \
  {                                                                             \
    _Pragma("unroll") for (int r = 0; r < 4; r++)                               \
        atomicAdd(&Gh[(16 * (i) + lhi * 4 + r) * 48 + 16 * (j) + lrow], Dv[r]); \
  }
  EMIT(D00, 0, 0); EMIT(D01, 0, 1); EMIT(D02, 0, 2);
  EMIT(D11, 1, 1); EMIT(D12, 1, 2); EMIT(D22, 2, 2);
#undef EMIT
}

// ---------------------------------------------------------------------------
// softmax of logits built from Gram; A[b][h][c][d]
// ---------------------------------------------------------------------------
__global__ __launch_bounds__(256) void k_attnsm(
    const float* __restrict__ G, const float* __restrict__ temp,
    float* __restrict__ A) {
  int idx = blockIdx.x * 256 + threadIdx.x;   // 768
  if (idx >= 4 * 8 * 24) return;
  int b = idx / (8 * 24);
  int rem = idx - b * 8 * 24;
  int h = rem / 24, c = rem % 24;
  const float* Gh = G + (size_t)(b * 8 + h) * 48 * 48;
  float tpr = temp[h];
  float nq = fmaxf(sqrtf(fmaxf(Gh[c * 48 + c], 0.f)), 1e-12f);
  float lg[24];
  float mx = -1e30f;
#pragma unroll
  for (int d = 0; d < 24; d++) {
    float nk = fmaxf(sqrtf(fmaxf(Gh[(24 + d) * 48 + 24 + d], 0.f)), 1e-12f);
    float l = Gh[c * 48 + 24 + d] / (nq * nk) * tpr;
    lg[d] = l;
    mx = fmaxf(mx, l);
  }
  float s = 0.f;
#pragma unroll
  for (int d = 0; d < 24; d++) { lg[d] = expf(lg[d] - mx); s += lg[d]; }
  float inv = 1.f / s;
  float* Ar = A + (size_t)idx * 24;
#pragma unroll
  for (int d = 0; d < 24; d++) Ar[d] = lg[d] * inv;
}

// ---------------------------------------------------------------------------
// Fold proj_w with per-head attention: M[b][o][h*24+d] (bf16)
// ---------------------------------------------------------------------------
__global__ __launch_bounds__(256) void k_foldM(
    const float* __restrict__ A, const float* __restrict__ P,
    unsigned short* __restrict__ M) {
  int idx = blockIdx.x * 256 + threadIdx.x;   // 4*192*192
  if (idx >= 4 * 192 * 192) return;
  int b = idx / (192 * 192);
  int rem = idx - b * 192 * 192;
  int o = rem / 192, cd = rem % 192;
  int h = cd / 24, d = cd % 24;
  const float* Ah = A + (size_t)(b * 8 + h) * 24 * 24;
  const float* Pr = P + o * 192 + h * 24;
  float s = 0.f;
#pragma unroll
  for (int ch = 0; ch < 24; ch++) s += Pr[ch] * Ah[ch * 24 + d];
  M[idx] = f2bf(s);
}

// ---------------------------------------------------------------------------
extern "C" void kernel_launch(void* const* d_in, const int* in_sizes, int n_in,
                              void* d_out, int out_size, void* d_ws,
                              size_t ws_size, hipStream_t stream) {
  const float* x          = (const float*)d_in[0];
  const float* ln2_w      = (const float*)d_in[1];
  const float* ln2_b      = (const float*)d_in[2];
  const float* qkv_w      = (const float*)d_in[3];
  const float* qkv_dw_w   = (const float*)d_in[4];
  const float* temperature= (const float*)d_in[5];
  const float* attn_proj_w= (const float*)d_in[6];
  const float* ln3_w      = (const float*)d_in[7];
  const float* ln3_b      = (const float*)d_in[8];
  const float* ffn_in_w   = (const float*)d_in[9];
  const float* ffn_dw_w   = (const float*)d_in[10];
  const float* ffn_out_w  = (const float*)d_in[11];

  unsigned char* ws = (unsigned char*)d_ws;
  size_t off = 0;
  auto alloc = [&](size_t bytes) -> void* {
    void* p = ws + off;
    off = (off + bytes + 255) & ~(size_t)255;
    return p;
  };
  // S1: qkv [B][N][576] -> h [B][N][1024]
  // S2: y [B][N][192] -> qkvd [B][N][576] -> y3 [B][N][192] -> g [B][N][512]
  unsigned short* S1   = (unsigned short*)alloc(134217728); // 4*16384*1024*2
  unsigned short* S2   = (unsigned short*)alloc(75497472);  // 4*16384*576*2
  unsigned short* out1b= (unsigned short*)alloc(25165824);  // 4*16384*192*2
  unsigned short* wq   = (unsigned short*)alloc(221184);
  unsigned short* wi   = (unsigned short*)alloc(393216);
  unsigned short* wo   = (unsigned short*)alloc(196608);
  unsigned short* Mw   = (unsigned short*)alloc(294912);
  float*          G    = (float*)alloc(294912);
  float*          Aat  = (float*)alloc(73728);

  k_convert_w<<<768, 256, 0, stream>>>(qkv_w, ffn_in_w, ffn_out_w, wq, wi, wo);
  k_zero<<<288, 256, 0, stream>>>(G, 4 * 8 * 48 * 48);

  // K1: LN2(x) -> y bf16 [B][N][192] (S2)
  k_ln<<<512, 256, 0, stream>>>(x, ln2_w, ln2_b, S2);

  // K2: qkv = y @ wq^T -> S1 [B][N][576]
  k_gemm<192, 192, 2, 0><<<dim3(64, 3, 4), 512, 0, stream>>>(
      S2, 192, wq, 0, nullptr, nullptr, S1, 576);

  // K3: dwconv on qkv -> qkvd (S2)
  k_dwconv<0, 4><<<dim3(32, 36, 4), 512, 0, stream>>>(S1, qkv_dw_w, S2);

  // K4: Gram of [q;k] -> G
  k_gram<<<dim3(16, 8, 4), 256, 0, stream>>>(S2, G);

  // K5: softmax -> Aat ; fold with proj -> M
  k_attnsm<<<3, 256, 0, stream>>>(G, temperature, Aat);
  k_foldM<<<576, 256, 0, stream>>>(Aat, attn_proj_w, Mw);

  // K6: out1b = bf16(x + M[b] @ v)  (v = qkvd cols 384..575)
  k_gemm<192, 192, 2, 2><<<dim3(64, 1, 4), 512, 0, stream>>>(
      S2 + 384, 576, Mw, 192 * 192, x, nullptr, out1b, 192);

  // K7: LN3(out1b) -> y3 bf16 [B][N][192] (S2, qkvd dead)
  k_ln_bf<<<256, 256, 0, stream>>>(out1b, ln3_w, ln3_b, S2);

  // K8: h = y3 @ wi^T -> S1 [B][N][1024]
  k_gemm<192, 128, 2, 0><<<dim3(64, 8, 4), 512, 0, stream>>>(
      S2, 192, wi, 0, nullptr, nullptr, S1, 1024);

  // K9: dwconv pairs + gelu gate -> g [B][N][512] (S2)
  k_dwconv<1, 4><<<dim3(32, 32, 4), 512, 0, stream>>>(S1, ffn_dw_w, S2);

  // K10: d_out = out1b + g @ wo^T  (fp32 [B][192][N])
  k_gemm<512, 64, 1, 3><<<dim3(128, 3, 4), 512, 0, stream>>>(
      S2, 512, wo, 0, nullptr, out1b, d_out, 0);
}